// Round 1
// baseline (2297.217 us; speedup 1.0000x reference)
//
#include <hip/hip_runtime.h>
#include <hip/hip_bf16.h>
#include <math.h>

// Problem constants (fixed by reference setup_inputs)
#define T_STEPS 1024
#define BATCH   256
#define E       128
#define K2E     256   // 2*E (input feature dim)
#define G4E     512   // 4*E (gates)

// ---------- math helpers ----------
__device__ __forceinline__ float sigmoidf_fast(float x) {
    return 1.0f / (1.0f + __expf(-x));
}
__device__ __forceinline__ float tanhf_fast(float x) {
    // tanh(x) = 1 - 2/(exp(2x)+1); saturates correctly at +/-inf
    return 1.0f - 2.0f / (1.0f + __expf(2.0f * x));
}
__device__ __forceinline__ float softplusf(float x) {
    // stable: max(x,0) + log1p(exp(-|x|))
    return fmaxf(x, 0.0f) + log1pf(__expf(-fabsf(x)));
}

// ---------- Phase 1: x_proj GEMM ----------
// xp[m, g] = sum_k x[m, k] * Wih[g, k] + (bih[g] + bhh[g])
// M = T*B = 262144, K = 256, N = 512.  A row-major MxK, B row-major NxK ("NT").
// Tile: BM=64, BN=64, BK=32; 256 threads; 4x4 micro-tile per thread.
__global__ __launch_bounds__(256)
void xproj_gemm(const float* __restrict__ x, const float* __restrict__ Wih,
                const float* __restrict__ bih, const float* __restrict__ bhh,
                float* __restrict__ xp_f32, __hip_bfloat16* __restrict__ xp_bf16,
                int use_bf16)
{
    // Transposed-staged tiles: [k][m] / [k][n]; pad 64->68 floats:
    // keeps 16B alignment for b128 reads (68*4=272B, %16==0) and breaks
    // the 8-way write conflict (bank = (4c + r) % 32 distinct per lane group).
    __shared__ float As[32][68];
    __shared__ float Bs[32][68];

    const int n0  = blockIdx.x * 64;   // N fast dim -> consecutive blocks share A tile in L2
    const int m0  = blockIdx.y * 64;
    const int tid = threadIdx.x;
    const int tx  = tid & 15;          // micro-tile col group
    const int ty  = tid >> 4;          // micro-tile row group
    const int lc  = tid & 7;           // float4 column for staging
    const int lr  = tid >> 3;          // row 0..31 for staging

    float acc[4][4] = {{0.0f}};

    for (int k0 = 0; k0 < K2E; k0 += 32) {
        #pragma unroll
        for (int rr = 0; rr < 2; ++rr) {
            const int r = lr + rr * 32;
            const float4 av = *reinterpret_cast<const float4*>(
                &x[(size_t)(m0 + r) * K2E + k0 + lc * 4]);
            const float4 bv = *reinterpret_cast<const float4*>(
                &Wih[(size_t)(n0 + r) * K2E + k0 + lc * 4]);
            As[lc * 4 + 0][r] = av.x;
            As[lc * 4 + 1][r] = av.y;
            As[lc * 4 + 2][r] = av.z;
            As[lc * 4 + 3][r] = av.w;
            Bs[lc * 4 + 0][r] = bv.x;
            Bs[lc * 4 + 1][r] = bv.y;
            Bs[lc * 4 + 2][r] = bv.z;
            Bs[lc * 4 + 3][r] = bv.w;
        }
        __syncthreads();

        #pragma unroll
        for (int kk = 0; kk < 32; ++kk) {
            const float4 a4 = *reinterpret_cast<const float4*>(&As[kk][ty * 4]);
            const float4 b4 = *reinterpret_cast<const float4*>(&Bs[kk][tx * 4]);
            const float aa[4] = {a4.x, a4.y, a4.z, a4.w};
            const float bb[4] = {b4.x, b4.y, b4.z, b4.w};
            #pragma unroll
            for (int i = 0; i < 4; ++i)
                #pragma unroll
                for (int j = 0; j < 4; ++j)
                    acc[i][j] = fmaf(aa[i], bb[j], acc[i][j]);
        }
        __syncthreads();
    }

    float bsum[4];
    #pragma unroll
    for (int j = 0; j < 4; ++j)
        bsum[j] = bih[n0 + tx * 4 + j] + bhh[n0 + tx * 4 + j];

    #pragma unroll
    for (int i = 0; i < 4; ++i) {
        const size_t row = (size_t)(m0 + ty * 4 + i);
        float4 v;
        v.x = acc[i][0] + bsum[0];
        v.y = acc[i][1] + bsum[1];
        v.z = acc[i][2] + bsum[2];
        v.w = acc[i][3] + bsum[3];
        if (!use_bf16) {
            *reinterpret_cast<float4*>(&xp_f32[row * G4E + n0 + tx * 4]) = v;
        } else {
            __hip_bfloat16* p = &xp_bf16[row * G4E + n0 + tx * 4];
            p[0] = __float2bfloat16(v.x);
            p[1] = __float2bfloat16(v.y);
            p[2] = __float2bfloat16(v.z);
            p[3] = __float2bfloat16(v.w);
        }
    }
}

// ---------- Phase 2: recurrence ----------
// One block per batch element; 512 threads, thread t owns gate row t.
// W_hh row (128 f32) held in VGPRs for the whole kernel (no weight reloads).
// h lives in LDS (broadcast reads); c lives in thread j<128's register.
template<bool XPBF16>
__global__ __launch_bounds__(512, 2)
void lstm_rec(const void* __restrict__ xp_, const float* __restrict__ h0,
              const float* __restrict__ c0, const float* __restrict__ Whh,
              float* __restrict__ out)
{
    const float*           xpf = reinterpret_cast<const float*>(xp_);
    const __hip_bfloat16*  xpb = reinterpret_cast<const __hip_bfloat16*>(xp_);

    const int b = blockIdx.x;   // batch element
    const int t = threadIdx.x;  // gate row 0..511 (i: 0-127, f: 128-255, g: 256-383, o: 384-511)

    __shared__ __align__(16) float h_lds[E];
    __shared__ __align__(16) float g_lds[G4E];

    // W_hh row t -> registers (fully unrolled, constant indices => stays in VGPRs)
    float w[E];
    {
        const float4* wr = reinterpret_cast<const float4*>(Whh + (size_t)t * E);
        #pragma unroll
        for (int i = 0; i < E / 4; ++i) {
            const float4 v = wr[i];
            w[4 * i + 0] = v.x;
            w[4 * i + 1] = v.y;
            w[4 * i + 2] = v.z;
            w[4 * i + 3] = v.w;
        }
    }

    float c = 0.0f;
    if (t < E) {
        h_lds[t] = h0[(size_t)b * E + t];
        c        = c0[(size_t)b * E + t];
    }
    __syncthreads();

    // prefetch xp for step 0
    float xpv;
    {
        const size_t i0 = (size_t)b * G4E + t;
        xpv = XPBF16 ? __bfloat162float(xpb[i0]) : xpf[i0];
    }

    for (int step = 0; step < T_STEPS; ++step) {
        // prefetch next step's xp (hidden under the FMA loop + barriers)
        float xpn = 0.0f;
        if (step + 1 < T_STEPS) {
            const size_t ni = ((size_t)(step + 1) * BATCH + b) * G4E + t;
            xpn = XPBF16 ? __bfloat162float(xpb[ni]) : xpf[ni];
        }

        // gate pre-activation: xp + h . W_hh[t,:]
        float acc = xpv;
        const float4* h4 = reinterpret_cast<const float4*>(h_lds);
        #pragma unroll
        for (int i = 0; i < E / 4; ++i) {
            const float4 hv = h4[i];   // LDS broadcast read (all lanes same addr)
            acc = fmaf(hv.x, w[4 * i + 0], acc);
            acc = fmaf(hv.y, w[4 * i + 1], acc);
            acc = fmaf(hv.z, w[4 * i + 2], acc);
            acc = fmaf(hv.w, w[4 * i + 3], acc);
        }

        // activation (wave-uniform branch: waves 4-5 are the g-gates -> tanh)
        const float a = (t < 2 * E || t >= 3 * E) ? sigmoidf_fast(acc)
                                                  : tanhf_fast(acc);
        if (t >= E) g_lds[t] = a;      // i-gates kept in-register by owner thread
        __syncthreads();

        if (t < E) {
            const float gi = a;
            const float gf = g_lds[1 * E + t];
            const float gg = g_lds[2 * E + t];
            const float go = g_lds[3 * E + t];
            c = fmaf(gf, c, gi * gg);
            const float h = go * tanhf_fast(c);
            h_lds[t] = h;
            out[((size_t)step * BATCH + b) * E + t] = softplusf(h);
        }
        __syncthreads();

        xpv = xpn;
    }
}

// ---------- launcher ----------
extern "C" void kernel_launch(void* const* d_in, const int* in_sizes, int n_in,
                              void* d_out, int out_size, void* d_ws, size_t ws_size,
                              hipStream_t stream)
{
    const float* x   = (const float*)d_in[0];
    const float* h0  = (const float*)d_in[1];
    const float* c0  = (const float*)d_in[2];
    const float* Wih = (const float*)d_in[3];
    const float* Whh = (const float*)d_in[4];
    const float* bih = (const float*)d_in[5];
    const float* bhh = (const float*)d_in[6];
    float*       out = (float*)d_out;

    const size_t xp_elems   = (size_t)T_STEPS * BATCH * G4E;     // 134M
    const bool   ws_fits_f32 = ws_size >= xp_elems * sizeof(float);

    dim3 g1(G4E / 64, (T_STEPS * BATCH) / 64);   // (8, 4096)
    dim3 b1(256);
    xproj_gemm<<<g1, b1, 0, stream>>>(x, Wih, bih, bhh,
                                      (float*)d_ws, (__hip_bfloat16*)d_ws,
                                      ws_fits_f32 ? 0 : 1);

    dim3 g2(BATCH);
    dim3 b2(G4E);
    if (ws_fits_f32)
        lstm_rec<false><<<g2, b2, 0, stream>>>(d_ws, h0, c0, Whh, out);
    else
        lstm_rec<true><<<g2, b2, 0, stream>>>(d_ws, h0, c0, Whh, out);
}